// Round 1
// 434.980 us; speedup vs baseline: 1.0226x; 1.0226x over previous
//
#include <hip/hip_runtime.h>

// Fixed dims: B=2048, D=1024, H=512, K=32, OUT=2
#define BB 2048
#define DD 1024
#define HH 512
#define KK 32

#define AS_GLOBAL __attribute__((address_space(1)))
#define AS_LDS    __attribute__((address_space(3)))

typedef __attribute__((ext_vector_type(8))) short short8;   // 8 bf16 (4 VGPRs)
typedef __attribute__((ext_vector_type(4))) float floatx4;  // MFMA acc

__device__ __forceinline__ float bf2f(unsigned short u) {
    union { unsigned int u; float f; } c; c.u = ((unsigned int)u) << 16; return c.f;
}
__device__ __forceinline__ unsigned short f2bf(float f) {
    union { float f; unsigned int u; } c; c.f = f;
    unsigned int u = c.u + 0x7FFFu + ((c.u >> 16) & 1u);
    return (unsigned short)(u >> 16);
}

// ---------------- workspace layout (byte offsets) ----------------
#define WOFF_XB    ((size_t)0)          // x bf16 [2048,1024]           4 MB
#define WOFF_W0T   ((size_t)4194304)    // w0^T bf16 [512,1024]         1 MB
#define WOFF_W1T   ((size_t)5242880)    // w1^T bf16 [512,512]          .5 MB
#define WOFF_WOUTT ((size_t)5767168)    // wout^T bf16 [1024,512]       1 MB
#define WOFF_WP0T  ((size_t)6815744)    // wp0^T bf16 [512,1024]        1 MB
#define WOFF_H0    ((size_t)7864320)    // h0 bf16 [2048,512]           2 MB
#define WOFF_H1    ((size_t)9961472)    // h1 bf16 [2048,512]           2 MB
#define WOFF_LG    ((size_t)12058624)   // logits_pre f32 [2048,1024]   8 MB
#define WOFF_NEWIN ((size_t)20447232)   // newin bf16 [2048,1024]       4 MB
#define WOFF_HP    ((size_t)24641536)   // hp bf16 [2048,512]           2 MB

// ---------------- prep: x convert + 4 weight transpose-converts ----------------
__global__ __launch_bounds__(256) void prep_kernel(
    const float* __restrict__ x,  const float* __restrict__ w0,
    const float* __restrict__ w1, const float* __restrict__ wout,
    const float* __restrict__ wp0, unsigned short* __restrict__ ws)
{
    const int blk = blockIdx.x;
    if (blk < 1024) {
        unsigned short* xb = ws + WOFF_XB / 2;
        const size_t base = (size_t)blk * 2048 + (size_t)threadIdx.x * 8;
        float4 v0 = *(const float4*)(x + base);
        float4 v1 = *(const float4*)(x + base + 4);
        ushort4 o0, o1;
        o0.x = f2bf(v0.x); o0.y = f2bf(v0.y); o0.z = f2bf(v0.z); o0.w = f2bf(v0.w);
        o1.x = f2bf(v1.x); o1.y = f2bf(v1.y); o1.z = f2bf(v1.z); o1.w = f2bf(v1.w);
        *(ushort4*)(xb + base) = o0;
        *(ushort4*)(xb + base + 4) = o1;
        return;
    }
    const float* src; unsigned short* dst; int Kd, N, t;
    if (blk < 1536)      { src = w0;   dst = ws + WOFF_W0T / 2;   Kd = 1024; N = 512;  t = blk - 1024; }
    else if (blk < 1792) { src = w1;   dst = ws + WOFF_W1T / 2;   Kd = 512;  N = 512;  t = blk - 1536; }
    else if (blk < 2304) { src = wout; dst = ws + WOFF_WOUTT / 2; Kd = 512;  N = 1024; t = blk - 1792; }
    else                 { src = wp0;  dst = ws + WOFF_WP0T / 2;  Kd = 1024; N = 512;  t = blk - 2304; }
    const int ntn = N / 32;
    const int kt = t / ntn, nt = t % ntn;
    __shared__ float tile[32][33];
    const int tx = threadIdx.x & 31, ty = threadIdx.x >> 5;   // 32 x 8
#pragma unroll
    for (int r = 0; r < 32; r += 8)
        tile[ty + r][tx] = src[(size_t)(kt * 32 + ty + r) * N + nt * 32 + tx];
    __syncthreads();
#pragma unroll
    for (int r = 0; r < 32; r += 8)
        dst[(size_t)(nt * 32 + ty + r) * Kd + kt * 32 + tx] = f2bf(tile[tx][ty + r]);
}

// ---------------- bf16 MFMA GEMM, 64x32 tile, BK=64, double-buffered ------------
// C[M,N] = act(A[M,K] @ BT[N,K]^T + bias). 256 thr = 4 waves; wave grid 2Mx2N,
// each wave owns 32x16 output (acc[2] of 16x16 frags).
// BN=32 (was 64) doubles the grid: N=512 GEMMs go 256->512 blocks = 2 blocks/CU,
// so one block's per-K-step barrier/vmcnt(0) drain overlaps the other block's
// MFMA (m114 wave-level overlap; absent at 1 block/CU).
// LDS layout per row: 16B chunk (row r, kchunk kc) at unit u = r*8 + (kc ^ (r&7)).
// global_load_lds staging (unit = tid) inverts this; frag ds_reads spread
// uniformly over banks (8 lanes / 4-bank group = conflict-free floor).
template <int RELU, int OUTBF>
__global__ __launch_bounds__(256) void gemm_mfma(
    const unsigned short* __restrict__ A,   // [M,K] bf16 row-major
    const unsigned short* __restrict__ BT,  // [N,K] bf16 row-major
    const float* __restrict__ bias,         // [N] f32
    void* __restrict__ Cv, int M, int N, int Kd)
{
    __shared__ __align__(16) unsigned short As[2][4096];   // 64 rows x 64 k  (2 x 8 KB)
    __shared__ __align__(16) unsigned short Bs[2][2048];   // 32 rows x 64 k  (2 x 4 KB)
    const int tid = threadIdx.x;
    const int bm = blockIdx.y * 64, bn = blockIdx.x * 32;
    const int wave = tid >> 6, lane = tid & 63;

    floatx4 acc[2] = {};

    // staging source mapping (inverse of the swizzle)
    const int sr = tid >> 3;                           // row 0..31
    const int skc = (tid & 7) ^ ((tid >> 3) & 7);      // permuted k-chunk
    const unsigned short* ga  = A  + (size_t)(bm + sr) * Kd + skc * 8;
    const unsigned short* ga2 = ga + (size_t)32 * Kd;
    const unsigned short* gb  = BT + (size_t)(bn + sr) * Kd + skc * 8;
    const int ldoff = wave * 512;                      // ushorts: wave-uniform base

    // fragment read indices: wave (wm in {0,32}, wn in {0,16})
    const int wm = (wave >> 1) * 32, wn = (wave & 1) * 16;
    const int fr = lane & 15, fq = lane >> 4;          // frag row, k-quad
    const int e = fr & 7;                              // row&7 (wm,16 are mult of 8)
    int ua[2];
    ua[0] = (wm + fr) * 8;
    ua[1] = (wm + 16 + fr) * 8;
    const int ub = (wn + fr) * 8;

    const int steps = Kd >> 6;

#define STAGE(buf, k0)                                                              \
    do {                                                                            \
        __builtin_amdgcn_global_load_lds((const AS_GLOBAL void*)(ga + (k0)),        \
            (AS_LDS void*)(&As[buf][0] + ldoff), 16, 0, 0);                         \
        __builtin_amdgcn_global_load_lds((const AS_GLOBAL void*)(ga2 + (k0)),       \
            (AS_LDS void*)(&As[buf][2048] + ldoff), 16, 0, 0);                      \
        __builtin_amdgcn_global_load_lds((const AS_GLOBAL void*)(gb + (k0)),        \
            (AS_LDS void*)(&Bs[buf][0] + ldoff), 16, 0, 0);                         \
    } while (0)

    STAGE(0, 0);
    __syncthreads();

    for (int s = 0; s < steps; ++s) {
        const int buf = s & 1;
        if (s + 1 < steps) STAGE((s + 1) & 1, (s + 1) << 6);   // prefetch overlaps MFMA
#pragma unroll
        for (int t = 0; t < 2; ++t) {
            const int kc = t * 4 + fq;
            const short8 a0 = *(const short8*)(&As[buf][0] + (size_t)(ua[0] + (kc ^ e)) * 8);
            const short8 a1 = *(const short8*)(&As[buf][0] + (size_t)(ua[1] + (kc ^ e)) * 8);
            const short8 bb = *(const short8*)(&Bs[buf][0] + (size_t)(ub    + (kc ^ e)) * 8);
            acc[0] = __builtin_amdgcn_mfma_f32_16x16x32_bf16(a0, bb, acc[0], 0, 0, 0);
            acc[1] = __builtin_amdgcn_mfma_f32_16x16x32_bf16(a1, bb, acc[1], 0, 0, 0);
        }
        __syncthreads();
    }
#undef STAGE

    // epilogue: C/D layout col = lane&15, row = (lane>>4)*4 + reg
    float* Cf = (float*)Cv;
    unsigned short* Cb = (unsigned short*)Cv;
    const int er = fq * 4, ec = fr;
    const int col = bn + wn + ec;
    const float bv = bias[col];
#pragma unroll
    for (int i = 0; i < 2; ++i) {
#pragma unroll
        for (int r = 0; r < 4; ++r) {
            const int row = bm + wm + i * 16 + er + r;
            float v = acc[i][r] + bv;
            if (RELU) v = fmaxf(v, 0.0f);
            if (OUTBF) Cb[(size_t)row * N + col] = f2bf(v);
            else       Cf[(size_t)row * N + col] = v;
        }
    }
}

// ---------------- wave reductions ----------------
__device__ __forceinline__ float wave_max(float v) {
#pragma unroll
    for (int o = 32; o; o >>= 1) v = fmaxf(v, __shfl_xor(v, o, 64));
    return v;
}
__device__ __forceinline__ float wave_sum(float v) {
#pragma unroll
    for (int o = 32; o; o >>= 1) v += __shfl_xor(v, o, 64);
    return v;
}

// ---------------- fused softmax(logits) + gumbel-softmax + max-K + mask ----------
// One BLOCK (4 waves) per row; wave w handles k = kk*4 + w (8 of the 32 k's),
// so the per-(b,k) arithmetic (incl. the 64-lane wave_sum order) is IDENTICAL
// to the 1-wave version -> bit-identical samples. Cross-wave combine is an
// order-independent max via LDS.
// Grid 2048 blocks (8/CU issued) vs the old 512 -> 4x wave parallelism, plus a
// register double-buffer prefetch of the next k-row to hide HBM latency.
// Algebra: sample_i = ep_i/t_i / sum, t = -log(u); ln2 factors cancel -> raw
// v_log_f32; division -> v_rcp_f32 (ratio, error cancels).
__global__ __launch_bounds__(256) void gumbel_fused(
    const float* __restrict__ lgpre,    // [B,D] logits pre-softmax (f32)
    const float* __restrict__ uniform,  // [B,K,D] f32
    const float* __restrict__ x,        // [B,D] f32
    float* __restrict__ masks,          // [B,D] f32 -> d_out+4096
    unsigned short* __restrict__ newin) // [B,D] bf16
{
    const int wave = threadIdx.x >> 6, lane = threadIdx.x & 63;
    const int b = blockIdx.x;
    __shared__ float lmk[4][1024];      // per-wave running max, 16 KB

    // ---- softmax over the row (selector probabilities p); redundant per wave,
    // identical results (reads are L2 hits for waves 1-3) ----
    float lp[16];
    const float* lrow = lgpre + (size_t)b * DD;
#pragma unroll
    for (int j = 0; j < 4; ++j)
        *(float4*)(lp + j * 4) = *(const float4*)(lrow + lane * 4 + j * 256);
    float M = -1e30f;
#pragma unroll
    for (int i = 0; i < 16; ++i) M = fmaxf(M, lp[i]);
    M = wave_max(M);
    float S = 0.f;
#pragma unroll
    for (int i = 0; i < 16; ++i) { lp[i] = __expf(lp[i] - M); S += lp[i]; }
    S = wave_sum(S);
    const float invS = 1.0f / S;
    float ep[16];
#pragma unroll
    for (int i = 0; i < 16; ++i) ep[i] = __expf(lp[i] * invS);   // exp(p_i)

    // ---- k-loop: 8 iters per wave, k = kk*4 + wave; double-buffered loads ----
    float mk[16] = {0.f,0.f,0.f,0.f,0.f,0.f,0.f,0.f,0.f,0.f,0.f,0.f,0.f,0.f,0.f,0.f};
    const float* up = uniform + (size_t)b * KK * DD + (size_t)wave * DD;
    float4 ucur[4], unext[4];
#pragma unroll
    for (int j = 0; j < 4; ++j)
        ucur[j] = *(const float4*)(up + lane * 4 + j * 256);
    for (int kk = 0; kk < 8; ++kk) {
        if (kk < 7) {
            const float* upn = up + (size_t)(kk + 1) * 4 * DD;
#pragma unroll
            for (int j = 0; j < 4; ++j)
                unext[j] = *(const float4*)(upn + lane * 4 + j * 256);
        }
        float sv[16], sloc = 0.f;
#pragma unroll
        for (int j = 0; j < 4; ++j) {
            const float uu[4] = {ucur[j].x, ucur[j].y, ucur[j].z, ucur[j].w};
#pragma unroll
            for (int q = 0; q < 4; ++q) {
                const float u = uu[q];
                // t' = -log2(u); v_log_f32 has poor RELATIVE accuracy for u->1
                // (abs err ~2^-22 on a ~0 result) — exactly the mask~1 samples —
                // so use the series there. -log2(u) = -v*(1/ln2 - v/(2ln2) + v^2/(3ln2))
                const float vv = u - 1.0f;
                const float tpoly = -vv * (1.4426950f + vv * (-0.7213475f + vv * 0.4808983f));
                const float tlog  = -__builtin_amdgcn_logf(u);   // v_log_f32 = log2
                const float t = (u > 0.984375f) ? tpoly : tlog;
                const float s = ep[j * 4 + q] * __builtin_amdgcn_rcpf(t);
                sv[j * 4 + q] = s;
                sloc += s;
            }
        }
        const float Sk = wave_sum(sloc);
        const float inv = __builtin_amdgcn_rcpf(Sk);
#pragma unroll
        for (int i = 0; i < 16; ++i) mk[i] = fmaxf(mk[i], sv[i] * inv);
#pragma unroll
        for (int j = 0; j < 4; ++j) ucur[j] = unext[j];
    }

    // ---- cross-wave max combine + outputs ----
#pragma unroll
    for (int j = 0; j < 4; ++j) {
        float4 mo; mo.x = mk[j*4]; mo.y = mk[j*4+1]; mo.z = mk[j*4+2]; mo.w = mk[j*4+3];
        *(float4*)(&lmk[wave][lane * 4 + j * 256]) = mo;
    }
    __syncthreads();
    const int d0 = threadIdx.x * 4;    // 256 thr x 4 elems = 1024
    const float4 m0 = *(const float4*)(&lmk[0][d0]);
    const float4 m1 = *(const float4*)(&lmk[1][d0]);
    const float4 m2 = *(const float4*)(&lmk[2][d0]);
    const float4 m3 = *(const float4*)(&lmk[3][d0]);
    float4 mm;
    mm.x = fmaxf(fmaxf(m0.x, m1.x), fmaxf(m2.x, m3.x));
    mm.y = fmaxf(fmaxf(m0.y, m1.y), fmaxf(m2.y, m3.y));
    mm.z = fmaxf(fmaxf(m0.z, m1.z), fmaxf(m2.z, m3.z));
    mm.w = fmaxf(fmaxf(m0.w, m1.w), fmaxf(m2.w, m3.w));
    const float4 xv = *(const float4*)(x + (size_t)b * DD + d0);
    *(float4*)(masks + (size_t)b * DD + d0) = mm;
    ushort4 nb;
    nb.x = f2bf(xv.x * mm.x); nb.y = f2bf(xv.y * mm.y);
    nb.z = f2bf(xv.z * mm.z); nb.w = f2bf(xv.w * mm.w);
    *(ushort4*)(newin + (size_t)b * DD + d0) = nb;
}

// ---------------- final: deep_out[B,2] = hp(bf16) @ wp1 + bp1 ----------------
__global__ __launch_bounds__(256) void final_kernel(
    const unsigned short* __restrict__ hp, const float* __restrict__ wp1,
    const float* __restrict__ bp1, float* __restrict__ out)
{
    const int wave = threadIdx.x >> 6, lane = threadIdx.x & 63;
    const int row = blockIdx.x * 4 + wave;
    const unsigned short* hrow = hp + (size_t)row * HH;
    float a0 = 0.f, a1 = 0.f;
#pragma unroll
    for (int j = 0; j < 8; ++j) {
        const int k = j * 64 + lane;
        const float h = bf2f(hrow[k]);
        const float2 w = *(const float2*)(wp1 + k * 2);
        a0 += h * w.x; a1 += h * w.y;
    }
    a0 = wave_sum(a0); a1 = wave_sum(a1);
    if (lane == 0) {
        out[row * 2 + 0] = a0 + bp1[0];
        out[row * 2 + 1] = a1 + bp1[1];
    }
}

extern "C" void kernel_launch(void* const* d_in, const int* in_sizes, int n_in,
                              void* d_out, int out_size, void* d_ws, size_t ws_size,
                              hipStream_t stream)
{
    (void)in_sizes; (void)n_in; (void)out_size; (void)ws_size;

    const float* x    = (const float*)d_in[0];
    const float* uni  = (const float*)d_in[1];
    const float* w0   = (const float*)d_in[2];
    const float* b0   = (const float*)d_in[3];
    const float* w1   = (const float*)d_in[4];
    const float* b1   = (const float*)d_in[5];
    const float* wout = (const float*)d_in[6];
    const float* bout = (const float*)d_in[7];
    const float* wp0  = (const float*)d_in[8];
    const float* bp0  = (const float*)d_in[9];
    const float* wp1  = (const float*)d_in[10];
    const float* bp1  = (const float*)d_in[11];

    unsigned char* ws = (unsigned char*)d_ws;
    unsigned short* xb    = (unsigned short*)(ws + WOFF_XB);
    unsigned short* w0T   = (unsigned short*)(ws + WOFF_W0T);
    unsigned short* w1T   = (unsigned short*)(ws + WOFF_W1T);
    unsigned short* woutT = (unsigned short*)(ws + WOFF_WOUTT);
    unsigned short* wp0T  = (unsigned short*)(ws + WOFF_WP0T);
    unsigned short* h0    = (unsigned short*)(ws + WOFF_H0);
    unsigned short* h1    = (unsigned short*)(ws + WOFF_H1);
    float*          lg    = (float*)(ws + WOFF_LG);
    unsigned short* newin = (unsigned short*)(ws + WOFF_NEWIN);
    unsigned short* hp    = (unsigned short*)(ws + WOFF_HP);

    float* out   = (float*)d_out;            // deep_out [2048,2]
    float* masks = out + (size_t)BB * 2;     // masks [2048,1024]

    prep_kernel<<<2816, 256, 0, stream>>>(x, w0, w1, wout, wp0, (unsigned short*)ws);

    gemm_mfma<1, 1><<<dim3(HH / 32, BB / 64), 256, 0, stream>>>(xb, w0T, b0, h0, BB, HH, DD);
    gemm_mfma<1, 1><<<dim3(HH / 32, BB / 64), 256, 0, stream>>>(h0, w1T, b1, h1, BB, HH, HH);
    gemm_mfma<0, 0><<<dim3(DD / 32, BB / 64), 256, 0, stream>>>(h1, woutT, bout, lg, BB, DD, HH);

    gumbel_fused<<<BB, 256, 0, stream>>>(lg, uni, x, masks, newin);

    gemm_mfma<1, 1><<<dim3(HH / 32, BB / 64), 256, 0, stream>>>(newin, wp0T, bp0, hp, BB, HH, DD);
    final_kernel<<<BB / 4, 256, 0, stream>>>(hp, wp1, bp1, out);
}